// Round 1
// baseline (137.989 us; speedup 1.0000x reference)
//
#include <hip/hip_runtime.h>

// Problem constants (from reference):
//   x:    [32, 64, 256, 256] fp32
//   coef: [64,1,1] fp32, bias: [64,1,1] fp32 (zeros)
//   out:  [32, 64, 128, 128] fp32
// out[b,c,ho,wo] = coef[c] * sum_{c'} sum_{2x2} x[b,c',2ho+dh,2wo+dw] + bias[c]

constexpr int B  = 32;
constexpr int C  = 64;
constexpr int H  = 256;
constexpr int W  = 256;
constexpr int HO = 128;
constexpr int WO = 128;

__global__ __launch_bounds__(256) void subsample_fused_kernel(
    const float* __restrict__ x,
    const float* __restrict__ coef,
    const float* __restrict__ bias,
    float* __restrict__ out)
{
    // One thread handles TWO adjacent output pixels (wo = 2*wp, 2*wp+1)
    // so each input-row read is a single coalesced float4 (16 B/lane).
    const int WO2 = WO / 2;  // 64 pixel-pairs per output row
    int t   = blockIdx.x * blockDim.x + threadIdx.x;
    int wp  = t % WO2;
    int tmp = t / WO2;
    int ho  = tmp % HO;
    int b   = tmp / HO;
    if (b >= B) return;

    // Input base: batch b, row 2*ho, col 4*wp (covers both 2x2 windows)
    const float* xb = x + (size_t)b * C * H * W + (size_t)(2 * ho) * W + 4 * wp;

    float s0 = 0.f, s1 = 0.f;  // pooled sums for the two output pixels
    #pragma unroll 8
    for (int c = 0; c < C; ++c) {
        const float* xc = xb + (size_t)c * (H * W);
        float4 r0 = *reinterpret_cast<const float4*>(xc);        // row 2ho
        float4 r1 = *reinterpret_cast<const float4*>(xc + W);    // row 2ho+1
        s0 += (r0.x + r0.y) + (r1.x + r1.y);
        s1 += (r0.z + r0.w) + (r1.z + r1.w);
    }

    // Broadcast to all 64 output channels with per-channel affine.
    float* ob = out + (size_t)b * C * HO * WO + (size_t)ho * WO + 2 * wp;
    #pragma unroll 8
    for (int c = 0; c < C; ++c) {
        float k  = coef[c];   // wave-uniform -> scalar load, L2-resident
        float bs = bias[c];
        float2 v = make_float2(fmaf(s0, k, bs), fmaf(s1, k, bs));
        *reinterpret_cast<float2*>(ob + (size_t)c * (HO * WO)) = v;
    }
}

extern "C" void kernel_launch(void* const* d_in, const int* in_sizes, int n_in,
                              void* d_out, int out_size, void* d_ws, size_t ws_size,
                              hipStream_t stream) {
    const float* x    = (const float*)d_in[0];
    const float* coef = (const float*)d_in[1];
    const float* bias = (const float*)d_in[2];
    float* out = (float*)d_out;

    const int total  = B * HO * (WO / 2);     // 262,144 threads
    const int block  = 256;
    const int grid   = total / block;         // 1024 blocks

    subsample_fused_kernel<<<grid, block, 0, stream>>>(x, coef, bias, out);
}

// Round 3
// 128.611 us; speedup vs baseline: 1.0729x; 1.0729x over previous
//
#include <hip/hip_runtime.h>

// Problem constants (from reference):
//   x:    [32, 64, 256, 256] fp32
//   coef: [64,1,1] fp32, bias: [64,1,1] fp32 (zeros)
//   out:  [32, 64, 128, 128] fp32
// out[b,c,ho,wo] = coef[c] * sum_{c'} sum_{2x2} x[b,c',2ho+dh,2wo+dw] + bias[c]
//
// Memory-bound: 512 MiB read + 128 MiB write = 671 MB total, floor ~107 us
// at the 6.3 TB/s copy ceiling. x/out are pure streaming (zero reuse), so
// mark them non-temporal to avoid L2/L3 pollution.
//
// NOTE: __builtin_nontemporal_load/store require true clang vector types,
// not HIP_vector_type structs -> use ext_vector_type typedefs.

constexpr int B  = 32;
constexpr int C  = 64;
constexpr int H  = 256;
constexpr int W  = 256;
constexpr int HO = 128;
constexpr int WO = 128;

typedef float floatx4 __attribute__((ext_vector_type(4)));
typedef float floatx2 __attribute__((ext_vector_type(2)));

__global__ __launch_bounds__(256) void subsample_fused_kernel(
    const float* __restrict__ x,
    const float* __restrict__ coef,
    const float* __restrict__ bias,
    float* __restrict__ out)
{
    // One thread handles TWO adjacent output pixels (wo = 2*wp, 2*wp+1)
    // so each input-row read is a single coalesced 16 B load (1 KiB/wave).
    const int WO2 = WO / 2;  // 64 pixel-pairs per output row
    int t   = blockIdx.x * blockDim.x + threadIdx.x;
    int wp  = t % WO2;
    int tmp = t / WO2;
    int ho  = tmp % HO;
    int b   = tmp / HO;
    if (b >= B) return;

    // Input base: batch b, row 2*ho, col 4*wp (covers both 2x2 windows)
    const float* xb = x + (size_t)b * C * H * W + (size_t)(2 * ho) * W + 4 * wp;

    float s0 = 0.f, s1 = 0.f;  // pooled sums for the two output pixels
    #pragma unroll 8
    for (int c = 0; c < C; ++c) {
        const float* xc = xb + (size_t)c * (H * W);
        // Non-temporal: x is 512 MiB streamed once; don't pollute L2/L3.
        floatx4 r0 = __builtin_nontemporal_load(reinterpret_cast<const floatx4*>(xc));
        floatx4 r1 = __builtin_nontemporal_load(reinterpret_cast<const floatx4*>(xc + W));
        s0 += (r0.x + r0.y) + (r1.x + r1.y);
        s1 += (r0.z + r0.w) + (r1.z + r1.w);
    }

    // Broadcast to all 64 output channels with per-channel affine.
    // coef/bias stay normal (cached, wave-uniform -> scalar loads).
    float* ob = out + (size_t)b * C * HO * WO + (size_t)ho * WO + 2 * wp;
    #pragma unroll 8
    for (int c = 0; c < C; ++c) {
        float k  = coef[c];
        float bs = bias[c];
        floatx2 v;
        v.x = fmaf(s0, k, bs);
        v.y = fmaf(s1, k, bs);
        __builtin_nontemporal_store(v, reinterpret_cast<floatx2*>(ob + (size_t)c * (HO * WO)));
    }
}

extern "C" void kernel_launch(void* const* d_in, const int* in_sizes, int n_in,
                              void* d_out, int out_size, void* d_ws, size_t ws_size,
                              hipStream_t stream) {
    const float* x    = (const float*)d_in[0];
    const float* coef = (const float*)d_in[1];
    const float* bias = (const float*)d_in[2];
    float* out = (float*)d_out;

    const int total  = B * HO * (WO / 2);     // 262,144 threads
    const int block  = 256;
    const int grid   = total / block;         // 1024 blocks

    subsample_fused_kernel<<<grid, block, 0, stream>>>(x, coef, bias, out);
}

// Round 4
// 122.392 us; speedup vs baseline: 1.1274x; 1.0508x over previous
//
#include <hip/hip_runtime.h>

// Problem constants (from reference):
//   x:    [32, 64, 256, 256] fp32
//   coef: [64,1,1] fp32, bias: [64,1,1] fp32 (zeros)
//   out:  [32, 64, 128, 128] fp32
// out[b,c,ho,wo] = coef[c] * sum_{c'} sum_{2x2} x[b,c',2ho+dh,2wo+dw] + bias[c]
//
// Memory-bound: 512 MiB read + 128 MiB write, floor ~107 us at 6.3 TB/s.
// This version: 2 output rows per thread so each wave reads 4 KiB contiguous
// per channel visit (better DRAM row locality) and writes 1 KiB contiguous.
// Loads are non-temporal (zero reuse, don't pollute L2/L3); stores are
// NORMAL so L2 batches the write-back stream.

constexpr int B  = 32;
constexpr int C  = 64;
constexpr int H  = 256;
constexpr int W  = 256;
constexpr int HO = 128;
constexpr int WO = 128;

typedef float floatx4 __attribute__((ext_vector_type(4)));

__global__ __launch_bounds__(256) void subsample_fused_kernel(
    const float* __restrict__ x,
    const float* __restrict__ coef,
    const float* __restrict__ bias,
    float* __restrict__ out)
{
    // Thread handles a 2(row) x 2(col) block of output pixels:
    //   output rows 2*hg, 2*hg+1 ; output cols 2*wp, 2*wp+1
    //   -> input rows 4*hg .. 4*hg+3, input cols 4*wp .. 4*wp+3
    // A wave (64 consecutive wp) covers full input rows: each of its 4 loads
    // is 1 KiB contiguous, and the 4 rows are adjacent -> 4 KiB/channel visit.
    const int WO2 = WO / 2;   // 64 pixel-pairs per output row
    const int HG  = HO / 2;   // 64 row-groups

    int t   = blockIdx.x * blockDim.x + threadIdx.x;
    int wp  = t % WO2;
    int tmp = t / WO2;
    int hg  = tmp % HG;
    int b   = tmp / HG;
    if (b >= B) return;

    const float* xb = x + (size_t)b * C * H * W + (size_t)(4 * hg) * W + 4 * wp;

    float s00 = 0.f, s01 = 0.f;   // output row 2hg,   cols 2wp / 2wp+1
    float s10 = 0.f, s11 = 0.f;   // output row 2hg+1, cols 2wp / 2wp+1
    #pragma unroll 4
    for (int c = 0; c < C; ++c) {
        const float* xc = xb + (size_t)c * (H * W);
        floatx4 r0 = __builtin_nontemporal_load(reinterpret_cast<const floatx4*>(xc));
        floatx4 r1 = __builtin_nontemporal_load(reinterpret_cast<const floatx4*>(xc + W));
        floatx4 r2 = __builtin_nontemporal_load(reinterpret_cast<const floatx4*>(xc + 2 * W));
        floatx4 r3 = __builtin_nontemporal_load(reinterpret_cast<const floatx4*>(xc + 3 * W));
        s00 += (r0.x + r0.y) + (r1.x + r1.y);
        s01 += (r0.z + r0.w) + (r1.z + r1.w);
        s10 += (r2.x + r2.y) + (r3.x + r3.y);
        s11 += (r2.z + r2.w) + (r3.z + r3.w);
    }

    // Broadcast to all 64 output channels with per-channel affine.
    // Wave writes out rows 2hg and 2hg+1 (adjacent): 1 KiB contiguous per c.
    float* ob = out + (size_t)b * C * HO * WO + (size_t)(2 * hg) * WO + 2 * wp;
    #pragma unroll 8
    for (int c = 0; c < C; ++c) {
        float k  = coef[c];
        float bs = bias[c];
        float* o0 = ob + (size_t)c * (HO * WO);
        *reinterpret_cast<float2*>(o0)      = make_float2(fmaf(s00, k, bs), fmaf(s01, k, bs));
        *reinterpret_cast<float2*>(o0 + WO) = make_float2(fmaf(s10, k, bs), fmaf(s11, k, bs));
    }
}

extern "C" void kernel_launch(void* const* d_in, const int* in_sizes, int n_in,
                              void* d_out, int out_size, void* d_ws, size_t ws_size,
                              hipStream_t stream) {
    const float* x    = (const float*)d_in[0];
    const float* coef = (const float*)d_in[1];
    const float* bias = (const float*)d_in[2];
    float* out = (float*)d_out;

    const int total = B * (HO / 2) * (WO / 2);   // 131,072 threads
    const int block = 256;
    const int grid  = total / block;             // 512 blocks

    subsample_fused_kernel<<<grid, block, 0, stream>>>(x, coef, bias, out);
}

// Round 5
// 113.757 us; speedup vs baseline: 1.2130x; 1.0759x over previous
//
#include <hip/hip_runtime.h>

// Problem constants (from reference):
//   x:    [32, 64, 256, 256] fp32
//   coef: [64,1,1] fp32, bias: [64,1,1] fp32 (zeros)
//   out:  [32, 64, 128, 128] fp32
// out[b,c,ho,wo] = coef[c] * sum_{c'} sum_{2x2} x[b,c',2ho+dh,2wo+dw] + bias[c]
//
// Two-pass split to separate the read and write streams:
//   pass 1: x (512 MiB, NT loads) -> pooled [B,HO,WO] (2 MiB, in d_ws)
//   pass 2: pooled (L2/L3-resident) * coef + bias -> out (128 MiB, NT stores)
// Floor: 537 MB reads + 134 MB writes at ~6.6-6.9 TB/s each ~= 100-107 us.

constexpr int B  = 32;
constexpr int C  = 64;
constexpr int H  = 256;
constexpr int W  = 256;
constexpr int HO = 128;
constexpr int WO = 128;

typedef float floatx4 __attribute__((ext_vector_type(4)));

// ---------------- Pass 1: channel-sum + 2x2 pool (pure read stream) --------
__global__ __launch_bounds__(256) void pool_reduce_kernel(
    const float* __restrict__ x,
    float* __restrict__ pooled)   // [B, HO, WO]
{
    // Thread handles a 2(row) x 2(col) block of pooled pixels:
    //   pooled rows 2*hg, 2*hg+1 ; cols 2*wp, 2*wp+1
    //   -> input rows 4*hg .. 4*hg+3, cols 4*wp .. 4*wp+3
    // Wave reads 4x 1 KiB contiguous per channel visit; block (4 waves,
    // consecutive hg) covers 16 KiB contiguous per channel plane.
    const int WO2 = WO / 2;   // 64
    const int HG  = HO / 2;   // 64

    int t   = blockIdx.x * blockDim.x + threadIdx.x;
    int wp  = t % WO2;
    int tmp = t / WO2;
    int hg  = tmp % HG;
    int b   = tmp / HG;
    if (b >= B) return;

    const float* xb = x + (size_t)b * C * H * W + (size_t)(4 * hg) * W + 4 * wp;

    float s00 = 0.f, s01 = 0.f;
    float s10 = 0.f, s11 = 0.f;
    #pragma unroll 4
    for (int c = 0; c < C; ++c) {
        const float* xc = xb + (size_t)c * (H * W);
        floatx4 r0 = __builtin_nontemporal_load(reinterpret_cast<const floatx4*>(xc));
        floatx4 r1 = __builtin_nontemporal_load(reinterpret_cast<const floatx4*>(xc + W));
        floatx4 r2 = __builtin_nontemporal_load(reinterpret_cast<const floatx4*>(xc + 2 * W));
        floatx4 r3 = __builtin_nontemporal_load(reinterpret_cast<const floatx4*>(xc + 3 * W));
        s00 += (r0.x + r0.y) + (r1.x + r1.y);
        s01 += (r0.z + r0.w) + (r1.z + r1.w);
        s10 += (r2.x + r2.y) + (r3.x + r3.y);
        s11 += (r2.z + r2.w) + (r3.z + r3.w);
    }

    float* pb = pooled + (size_t)b * HO * WO + (size_t)(2 * hg) * WO + 2 * wp;
    *reinterpret_cast<float2*>(pb)      = make_float2(s00, s01);
    *reinterpret_cast<float2*>(pb + WO) = make_float2(s10, s11);
}

// ---------------- Pass 2: broadcast + affine (pure write stream) -----------
__global__ __launch_bounds__(256) void broadcast_affine_kernel(
    const float* __restrict__ pooled,  // [B, HO, WO], L2/L3-resident
    const float* __restrict__ coef,
    const float* __restrict__ bias,
    float* __restrict__ out)           // [B, C, HO, WO]
{
    // One float4 of output per iteration; flat vec index i maps exactly to
    // out layout: i = ((b*C + c)*HO + ho)*(WO/4) + wq.
    const size_t nvec   = (size_t)B * C * HO * (WO / 4);    // 8,388,608
    const size_t stride = (size_t)gridDim.x * blockDim.x;

    for (size_t i = blockIdx.x * (size_t)blockDim.x + threadIdx.x;
         i < nvec; i += stride) {
        int wq = (int)(i & 31);          // WO/4 = 32
        int ho = (int)((i >> 5) & 127);  // HO = 128
        int c  = (int)((i >> 12) & 63);  // C = 64
        int b  = (int)(i >> 18);

        floatx4 p = *reinterpret_cast<const floatx4*>(
            pooled + ((size_t)b * HO + ho) * WO + wq * 4);
        float k  = coef[c];
        float bs = bias[c];
        floatx4 v;
        v.x = fmaf(p.x, k, bs);
        v.y = fmaf(p.y, k, bs);
        v.z = fmaf(p.z, k, bs);
        v.w = fmaf(p.w, k, bs);
        __builtin_nontemporal_store(v, reinterpret_cast<floatx4*>(out + i * 4));
    }
}

// ---------------- Fallback: R4 fused kernel (if ws too small) --------------
__global__ __launch_bounds__(256) void subsample_fused_kernel(
    const float* __restrict__ x,
    const float* __restrict__ coef,
    const float* __restrict__ bias,
    float* __restrict__ out)
{
    const int WO2 = WO / 2;
    const int HG  = HO / 2;
    int t   = blockIdx.x * blockDim.x + threadIdx.x;
    int wp  = t % WO2;
    int tmp = t / WO2;
    int hg  = tmp % HG;
    int b   = tmp / HG;
    if (b >= B) return;

    const float* xb = x + (size_t)b * C * H * W + (size_t)(4 * hg) * W + 4 * wp;
    float s00 = 0.f, s01 = 0.f, s10 = 0.f, s11 = 0.f;
    #pragma unroll 4
    for (int c = 0; c < C; ++c) {
        const float* xc = xb + (size_t)c * (H * W);
        floatx4 r0 = __builtin_nontemporal_load(reinterpret_cast<const floatx4*>(xc));
        floatx4 r1 = __builtin_nontemporal_load(reinterpret_cast<const floatx4*>(xc + W));
        floatx4 r2 = __builtin_nontemporal_load(reinterpret_cast<const floatx4*>(xc + 2 * W));
        floatx4 r3 = __builtin_nontemporal_load(reinterpret_cast<const floatx4*>(xc + 3 * W));
        s00 += (r0.x + r0.y) + (r1.x + r1.y);
        s01 += (r0.z + r0.w) + (r1.z + r1.w);
        s10 += (r2.x + r2.y) + (r3.x + r3.y);
        s11 += (r2.z + r2.w) + (r3.z + r3.w);
    }
    float* ob = out + (size_t)b * C * HO * WO + (size_t)(2 * hg) * WO + 2 * wp;
    #pragma unroll 8
    for (int c = 0; c < C; ++c) {
        float k = coef[c], bs = bias[c];
        float* o0 = ob + (size_t)c * (HO * WO);
        *reinterpret_cast<float2*>(o0)      = make_float2(fmaf(s00, k, bs), fmaf(s01, k, bs));
        *reinterpret_cast<float2*>(o0 + WO) = make_float2(fmaf(s10, k, bs), fmaf(s11, k, bs));
    }
}

extern "C" void kernel_launch(void* const* d_in, const int* in_sizes, int n_in,
                              void* d_out, int out_size, void* d_ws, size_t ws_size,
                              hipStream_t stream) {
    const float* x    = (const float*)d_in[0];
    const float* coef = (const float*)d_in[1];
    const float* bias = (const float*)d_in[2];
    float* out = (float*)d_out;

    const size_t pooled_bytes = (size_t)B * HO * WO * sizeof(float);  // 2 MiB

    if (d_ws != nullptr && ws_size >= pooled_bytes) {
        float* pooled = (float*)d_ws;

        // Pass 1: 131,072 threads = 512 blocks (2 blocks/CU)
        const int total1 = B * (HO / 2) * (WO / 2);
        pool_reduce_kernel<<<total1 / 256, 256, 0, stream>>>(x, pooled);

        // Pass 2: grid-stride, 2048 blocks (8 blocks/CU), 16 float4/thread
        broadcast_affine_kernel<<<2048, 256, 0, stream>>>(pooled, coef, bias, out);
    } else {
        const int total = B * (HO / 2) * (WO / 2);
        subsample_fused_kernel<<<total / 256, 256, 0, stream>>>(x, coef, bias, out);
    }
}